// Round 1
// baseline (324.054 us; speedup 1.0000x reference)
//
#include <hip/hip_runtime.h>
#include <hip/hip_bf16.h>
#include <math.h>

// Problem dims
#define Bn 16
#define Sn 128
#define Rn 4
#define Ln 50
#define En 64
#define Hn 64
#define Vn 1000
#define Dn 65           // E+1
#define G3 192          // 3*H
#define PH1n 256
#define PH2n 64
#define NSEQ (Bn*Sn*Rn) // 8192
#define NROW (Bn*Sn)    // 2048

__device__ __forceinline__ float sigmoidf_(float x) { return 1.0f / (1.0f + expf(-x)); }

// ---------------------------------------------------------------------------
// Kernel A: precompute input-projection tables
//   pre[v][j] = bi[j] + sum_e emb[v][e] * Wi[e][j]   (rows 0..63 of Wi only)
// grid (1000, 2) x 192 threads; blockIdx.y: 0 -> (Wi_h,bi_h)->pre_h, 1 -> x
// ---------------------------------------------------------------------------
__global__ __launch_bounds__(192) void precompute_tab(
    const float* __restrict__ emb,
    const float* __restrict__ Wi_h, const float* __restrict__ bi_h,
    const float* __restrict__ Wi_x, const float* __restrict__ bi_x,
    float* __restrict__ pre_h, float* __restrict__ pre_x)
{
    const int v = blockIdx.x;
    const int j = threadIdx.x;            // 0..191
    const float* Wi = blockIdx.y ? Wi_x : Wi_h;
    const float* bi = blockIdx.y ? bi_x : bi_h;
    float* outp = blockIdx.y ? pre_x : pre_h;
    __shared__ float e_l[En];
    if (j < En) e_l[j] = emb[v * En + j];
    __syncthreads();
    float a = bi[j];
#pragma unroll 8
    for (int k = 0; k < En; ++k) a = fmaf(e_l[k], Wi[k * G3 + j], a);
    outp[v * G3 + j] = a;
}

// ---------------------------------------------------------------------------
// Kernel B: fused GRUs.
//   blocks 0..255   : peer-history GRU, 32 sequences per block, 50 steps.
//   blocks 256..271 : intra GRU, one student sequence per block, 128 steps.
// ---------------------------------------------------------------------------
#define GP 32   // peer sequences per block

__global__ __launch_bounds__(256) void gru_fused(
    const float* __restrict__ pre_h, const float* __restrict__ pre_x,
    const int*   __restrict__ inter_his, const int* __restrict__ inter_len,
    const float* __restrict__ Wh_h, const float* __restrict__ bh_h,
    const float* __restrict__ Wi_h,          // row 64 = label weights
    const int*   __restrict__ intra_x, const float* __restrict__ y,
    const float* __restrict__ Wh_x, const float* __restrict__ bh_x,
    const float* __restrict__ Wi_x,
    float* __restrict__ M_rv, float* __restrict__ h_x)
{
    // ---- peer shared ----
    __shared__ float Wl[3][64][64];                 // [gate][k][j]
    __shared__ float __align__(16) h_l[64][36];     // [k][row], pad 36 for banks
    __shared__ int   ids[GP][Ln];
    __shared__ float labs[GP][Ln];
    __shared__ int   lens[GP];
    // ---- intra shared ----
    __shared__ float __align__(16) h_i[64];
    __shared__ int   xid[Sn];
    __shared__ float ysh[Sn];
    __shared__ float gh_b[G3];
    __shared__ float gx_b[G3];

    const int tid = threadIdx.x;

    if (blockIdx.x < 256) {
        // =============== PEER GRU ===============
        const int seq0 = blockIdx.x * GP;
        // stage Wh_h [64][192] -> Wl[gate][k][j]
        for (int i = tid; i < 64 * G3; i += 256) {
            int k = i / G3, c = i % G3;
            Wl[c >> 6][k][c & 63] = Wh_h[i];
        }
        // stage ids/labels: inter_his flat ((seq*50+t)*2 + {0,1})
        for (int i = tid; i < GP * Ln; i += 256) {
            int r = i / Ln, t = i % Ln;
            int base = ((seq0 + r) * Ln + t) * 2;
            ids[r][t]  = inter_his[base];
            labs[r][t] = (float)inter_his[base + 1];
        }
        if (tid < GP) lens[tid] = inter_len[seq0 + tid];
        for (int i = tid; i < 64 * 36; i += 256) (&h_l[0][0])[i] = 0.0f;
        __syncthreads();

        const int j  = tid & 63;
        const int rg = tid >> 6;     // 0..3 (uniform per wave)
        const int r0 = rg * 8;
        const float bhr = bh_h[j], bhz = bh_h[64 + j], bhn = bh_h[128 + j];
        const float wlr = Wi_h[64 * G3 + j];
        const float wlz = Wi_h[64 * G3 + 64 + j];
        const float wln = Wi_h[64 * G3 + 128 + j];
        float hprev[8];
#pragma unroll
        for (int i = 0; i < 8; ++i) hprev[i] = 0.0f;

        const float4* h4v = (const float4*)&h_l[0][0];  // row k at k*9 float4s
        const int f0 = rg * 2;

        for (int t = 0; t < Ln; ++t) {
            // input-side pre-activations (from L2-resident table), issued early
            float xr[8], xz[8], xn[8];
#pragma unroll
            for (int i = 0; i < 8; ++i) {
                int id = ids[r0 + i][t];
                float lb = labs[r0 + i][t];
                const float* p = pre_h + id * G3;
                xr[i] = fmaf(lb, wlr, p[j]);
                xz[i] = fmaf(lb, wlz, p[64 + j]);
                xn[i] = fmaf(lb, wln, p[128 + j]);
            }
            // recurrent matmul: gh[r][j-triple] = bh + sum_k h[r][k]*Wh[k][...]
            float ar[8], az[8], an[8];
#pragma unroll
            for (int i = 0; i < 8; ++i) { ar[i] = bhr; az[i] = bhz; an[i] = bhn; }
#pragma unroll 4
            for (int k = 0; k < 64; ++k) {
                float4 ha = h4v[k * 9 + f0];
                float4 hb = h4v[k * 9 + f0 + 1];
                float wr = Wl[0][k][j], wz = Wl[1][k][j], wn = Wl[2][k][j];
                float hv[8] = {ha.x, ha.y, ha.z, ha.w, hb.x, hb.y, hb.z, hb.w};
#pragma unroll
                for (int i = 0; i < 8; ++i) {
                    ar[i] = fmaf(hv[i], wr, ar[i]);
                    az[i] = fmaf(hv[i], wz, az[i]);
                    an[i] = fmaf(hv[i], wn, an[i]);
                }
            }
            __syncthreads();   // all reads of h(t) done before overwriting
#pragma unroll
            for (int i = 0; i < 8; ++i) {
                float r = sigmoidf_(xr[i] + ar[i]);
                float z = sigmoidf_(xz[i] + az[i]);
                float n = tanhf(fmaf(r, an[i], xn[i]));
                float h = (1.0f - z) * n + z * hprev[i];
                hprev[i] = h;
                h_l[j][r0 + i] = h;                       // transposed store
                if (t == lens[r0 + i] - 1)
                    M_rv[(seq0 + r0 + i) * Hn + j] = h;
            }
            __syncthreads();
        }
    } else {
        // =============== INTRA GRU ===============
        const int b = blockIdx.x - 256;   // 0..15
        for (int i = tid; i < Sn; i += 256) {
            xid[i] = intra_x[b * Sn + i];
            ysh[i] = (i == 0) ? 0.0f : y[b * Sn + i - 1];
        }
        if (tid < 64) h_i[tid] = 0.0f;
        __syncthreads();

        const int j = tid;                 // 0..191 active
        float whcol[64];
        float bh = 0.0f, wlab = 0.0f;
        if (j < G3) {
#pragma unroll 8
            for (int k = 0; k < 64; ++k) whcol[k] = Wh_x[k * G3 + j];
            bh   = bh_x[j];
            wlab = Wi_x[64 * G3 + j];
        }
        const float4* h4 = (const float4*)h_i;
        for (int t = 0; t < Sn; ++t) {
            if (j < G3) {
                float acch = bh;
#pragma unroll
                for (int k4 = 0; k4 < 16; ++k4) {
                    float4 h4x = h4[k4];
                    acch = fmaf(h4x.x, whcol[4 * k4 + 0], acch);
                    acch = fmaf(h4x.y, whcol[4 * k4 + 1], acch);
                    acch = fmaf(h4x.z, whcol[4 * k4 + 2], acch);
                    acch = fmaf(h4x.w, whcol[4 * k4 + 3], acch);
                }
                gh_b[j] = acch;
                gx_b[j] = fmaf(ysh[t], wlab, pre_x[xid[t] * G3 + j]);
            }
            __syncthreads();
            if (j < 64) {
                float r = sigmoidf_(gx_b[j] + gh_b[j]);
                float z = sigmoidf_(gx_b[64 + j] + gh_b[64 + j]);
                float n = tanhf(fmaf(r, gh_b[128 + j], gx_b[128 + j]));
                float h = (1.0f - z) * n + z * h_i[j];
                h_i[j] = h;
                h_x[(b * Sn + t) * Hn + j] = h;
            }
            __syncthreads();
        }
    }
}

// ---------------------------------------------------------------------------
// Kernel C: attention over R peers + output MLP; one (b,s) row per block.
// ---------------------------------------------------------------------------
__global__ __launch_bounds__(256) void attn_mlp(
    const float* __restrict__ h_x, const float* __restrict__ M_rv,
    const float* __restrict__ emb, const int* __restrict__ inter_r,
    const float* __restrict__ y,
    const float* __restrict__ Wq,
    const float* __restrict__ Wo, const float* __restrict__ bo,
    const float* __restrict__ W1, const float* __restrict__ b1,
    const float* __restrict__ W2, const float* __restrict__ b2,
    const float* __restrict__ W3, const float* __restrict__ b3,
    float* __restrict__ out)
{
    const int idx = blockIdx.x;   // row in [0, 2048)
    const int tid = threadIdx.x;
    __shared__ float sh[64], ql[64], Ml[4][64], scl[4], al[4];
    __shared__ float vv[132], ol[64], z1[PH1n], z2[64];
    __shared__ int   rid[4];
    __shared__ float rlab[4];

    if (tid < 64) sh[tid] = h_x[idx * Hn + tid];
    { int r = tid >> 6, j = tid & 63; Ml[r][j] = M_rv[(idx * Rn + r) * Hn + j]; }
    if (tid < 4) {
        rid[tid]  = inter_r[(idx * Rn + tid) * 2];
        rlab[tid] = (float)inter_r[(idx * Rn + tid) * 2 + 1];
    }
    __syncthreads();
    if (tid < 64) {
        float a = 0.0f;
#pragma unroll 8
        for (int k = 0; k < 64; ++k) a = fmaf(sh[k], Wq[k * Hn + tid], a);
        ql[tid] = a;
    }
    __syncthreads();
    if (tid < 4) {
        float a = 0.0f;
#pragma unroll 8
        for (int k = 0; k < 64; ++k) a = fmaf(ql[k], Ml[tid][k], a);
        scl[tid] = a * 0.125f;   // / sqrt(64)
    }
    __syncthreads();
    if (tid == 0) {
        float m = fmaxf(fmaxf(scl[0], scl[1]), fmaxf(scl[2], scl[3]));
        float s = 0.0f;
        float e[4];
#pragma unroll
        for (int r = 0; r < 4; ++r) { e[r] = expf(scl[r] - m); s += e[r]; }
        float inv = 1.0f / s;
#pragma unroll
        for (int r = 0; r < 4; ++r) al[r] = e[r] * inv;
    }
    __syncthreads();
    // v = sum_r alpha[r] * concat(M_rv[r] (64), emb[rid[r]] (64), rlab[r] (1))
    if (tid < 129) {
        float a = 0.0f;
#pragma unroll
        for (int r = 0; r < 4; ++r) {
            float val;
            if (tid < 64)       val = Ml[r][tid];
            else if (tid < 128) val = emb[rid[r] * En + (tid - 64)];
            else                val = rlab[r];
            a = fmaf(al[r], val, a);
        }
        vv[tid] = a;
    }
    __syncthreads();
    if (tid < 64) {
        float a = bo[tid];
#pragma unroll 8
        for (int k = 0; k < 64; ++k)  a = fmaf(sh[k], Wo[k * Hn + tid], a);
        for (int k = 0; k < 129; ++k) a = fmaf(vv[k], Wo[(64 + k) * Hn + tid], a);
        ol[tid] = tanhf(a);
    }
    __syncthreads();
    {
        float a = b1[tid];
#pragma unroll 8
        for (int k = 0; k < 64; ++k) a = fmaf(ol[k], W1[k * PH1n + tid], a);
        z1[tid] = fmaxf(a, 0.0f);
    }
    __syncthreads();
    if (tid < 64) {
        float a = b2[tid];
#pragma unroll 8
        for (int k = 0; k < PH1n; ++k) a = fmaf(z1[k], W2[k * PH2n + tid], a);
        z2[tid] = fmaxf(a, 0.0f);
    }
    __syncthreads();
    if (tid == 0) {
        float a = b3[0];
#pragma unroll 8
        for (int k = 0; k < 64; ++k) a = fmaf(z2[k], W3[k], a);
        out[idx] = 1.0f / (1.0f + expf(-a));
        out[NROW + idx] = y[idx];    // y_sel passthrough (mask is all ones)
    }
}

// ---------------------------------------------------------------------------
extern "C" void kernel_launch(void* const* d_in, const int* in_sizes, int n_in,
                              void* d_out, int out_size, void* d_ws, size_t ws_size,
                              hipStream_t stream) {
    const int*   intra_x   = (const int*)d_in[0];
    const int*   inter_his = (const int*)d_in[1];
    const int*   inter_r   = (const int*)d_in[2];
    const float* y         = (const float*)d_in[3];
    // d_in[4] = mask (all ones) unused
    const int*   inter_len = (const int*)d_in[5];
    const float* emb  = (const float*)d_in[6];
    const float* Wi_h = (const float*)d_in[7];
    const float* Wh_h = (const float*)d_in[8];
    const float* bi_h = (const float*)d_in[9];
    const float* bh_h = (const float*)d_in[10];
    const float* Wi_x = (const float*)d_in[11];
    const float* Wh_x = (const float*)d_in[12];
    const float* bi_x = (const float*)d_in[13];
    const float* bh_x = (const float*)d_in[14];
    const float* Wq = (const float*)d_in[15];
    const float* Wo = (const float*)d_in[16];
    const float* bo = (const float*)d_in[17];
    const float* W1 = (const float*)d_in[18];
    const float* b1 = (const float*)d_in[19];
    const float* W2 = (const float*)d_in[20];
    const float* b2 = (const float*)d_in[21];
    const float* W3 = (const float*)d_in[22];
    const float* b3 = (const float*)d_in[23];

    float* out = (float*)d_out;
    float* ws  = (float*)d_ws;
    float* pre_h = ws;                       // 1000*192
    float* pre_x = ws + 192000;              // 1000*192
    float* M_rv  = ws + 384000;              // 8192*64
    float* h_x   = ws + 384000 + 524288;     // 16*128*64

    precompute_tab<<<dim3(Vn, 2), 192, 0, stream>>>(emb, Wi_h, bi_h, Wi_x, bi_x,
                                                    pre_h, pre_x);
    gru_fused<<<272, 256, 0, stream>>>(pre_h, pre_x, inter_his, inter_len,
                                       Wh_h, bh_h, Wi_h,
                                       intra_x, y, Wh_x, bh_x, Wi_x,
                                       M_rv, h_x);
    attn_mlp<<<NROW, 256, 0, stream>>>(h_x, M_rv, emb, inter_r, y,
                                       Wq, Wo, bo, W1, b1, W2, b2, W3, b3, out);
}

// Round 2
// 247.023 us; speedup vs baseline: 1.3118x; 1.3118x over previous
//
#include <hip/hip_runtime.h>
#include <hip/hip_bf16.h>
#include <math.h>

// Problem dims
#define Bn 16
#define Sn 128
#define Rn 4
#define Ln 50
#define En 64
#define Hn 64
#define Vn 1000
#define G3 192          // 3*H
#define PH1n 256
#define PH2n 64
#define NSEQ (Bn*Sn*Rn) // 8192
#define NROW (Bn*Sn)    // 2048
#define GP 16           // peer sequences per block (MFMA M-tile)

typedef short bf16x8 __attribute__((ext_vector_type(8)));
typedef float f32x4  __attribute__((ext_vector_type(4)));

__device__ __forceinline__ unsigned short f2bf(float x) {
    union { float f; unsigned u; } v; v.f = x;
    unsigned r = v.u + 0x7FFF + ((v.u >> 16) & 1);   // RNE
    return (unsigned short)(r >> 16);
}
__device__ __forceinline__ float fsig(float x)  { return 1.0f / (1.0f + __expf(-x)); }
__device__ __forceinline__ float ftanh(float x) { float e = __expf(2.0f * x); return 1.0f - 2.0f / (e + 1.0f); }

// ---------------------------------------------------------------------------
// Kernel A: precompute input-projection tables
//   pre[v][j] = bi[j] + sum_e emb[v][e] * Wi[e][j]   (rows 0..63 of Wi)
// ---------------------------------------------------------------------------
__global__ __launch_bounds__(192) void precompute_tab(
    const float* __restrict__ emb,
    const float* __restrict__ Wi_h, const float* __restrict__ bi_h,
    const float* __restrict__ Wi_x, const float* __restrict__ bi_x,
    float* __restrict__ pre_h, float* __restrict__ pre_x)
{
    const int v = blockIdx.x;
    const int j = threadIdx.x;
    const float* Wi = blockIdx.y ? Wi_x : Wi_h;
    const float* bi = blockIdx.y ? bi_x : bi_h;
    float* outp = blockIdx.y ? pre_x : pre_h;
    __shared__ float e_l[En];
    if (j < En) e_l[j] = emb[v * En + j];
    __syncthreads();
    float a = bi[j];
#pragma unroll 8
    for (int k = 0; k < En; ++k) a = fmaf(e_l[k], Wi[k * G3 + j], a);
    outp[v * G3 + j] = a;
}

// ---------------------------------------------------------------------------
// Kernel B: fused GRUs.
//   blocks 0..15    : intra GRU (fp32), one student sequence per block.
//   blocks 16..527  : peer-history GRU via bf16 MFMA, 16 sequences per block.
// ---------------------------------------------------------------------------
__global__ __launch_bounds__(256) void gru_fused(
    const float* __restrict__ pre_h, const float* __restrict__ pre_x,
    const int*   __restrict__ inter_his, const int* __restrict__ inter_len,
    const float* __restrict__ Wh_h, const float* __restrict__ bh_h,
    const float* __restrict__ Wi_h,
    const int*   __restrict__ intra_x, const float* __restrict__ y,
    const float* __restrict__ Wh_x, const float* __restrict__ bh_x,
    const float* __restrict__ Wi_x,
    float* __restrict__ M_rv, float* __restrict__ h_x)
{
    // peer shared
    __shared__ __align__(16) unsigned short h16s[GP * 64];   // bf16 h, XOR-swizzled
    __shared__ int   ids_l[GP][Ln];
    __shared__ float labs_l[GP][Ln];
    // intra shared
    __shared__ __align__(16) float h_i[64];
    __shared__ int   xid[Sn];
    __shared__ float ysh[Sn];
    __shared__ float gh_b[G3];
    __shared__ float gx_b[G3];

    const int tid = threadIdx.x;

    if (blockIdx.x >= 16) {
        // =============== PEER GRU (MFMA) ===============
        const int pb = blockIdx.x - 16;
        const int seq0 = pb * GP;
        for (int i = tid; i < GP * Ln; i += 256) {
            int r = i / Ln, t = i % Ln;
            int base = ((seq0 + r) * Ln + t) * 2;
            ids_l[r][t]  = inter_his[base];
            labs_l[r][t] = (float)inter_his[base + 1];
        }
        for (int i = tid; i < GP * 64; i += 256) h16s[i] = 0;
        __syncthreads();

        const int lane = tid & 63, w = tid >> 6;
        const int n_ = lane & 15, kb = lane >> 4;
        const int jh = w * 16 + n_;           // this wave's hidden-column
        // B fragments: Wh[64][192] -> 3 gate-tiles x 2 K-halves, bf16, in VGPRs
        bf16x8 bfr[3][2];
#pragma unroll
        for (int g = 0; g < 3; ++g)
#pragma unroll
            for (int kh = 0; kh < 2; ++kh) {
                bf16x8 v;
#pragma unroll
                for (int i = 0; i < 8; ++i)
                    v[i] = (short)f2bf(Wh_h[(kh * 32 + kb * 8 + i) * G3 + g * 64 + jh]);
                bfr[g][kh] = v;
            }
        const float bhr = bh_h[jh], bhz = bh_h[64 + jh], bhn = bh_h[128 + jh];
        const float wlr = Wi_h[64 * G3 + jh];
        const float wlz = Wi_h[64 * G3 + 64 + jh];
        const float wln = Wi_h[64 * G3 + 128 + jh];
        const int rbase = kb * 4;             // C rows owned by this lane
        int lenr[4];
#pragma unroll
        for (int q = 0; q < 4; ++q) lenr[q] = inter_len[seq0 + rbase + q];
        float hprev[4] = {0.f, 0.f, 0.f, 0.f};
        // A-fragment LDS offsets (m = lane&15, swizzle ^((m&7)<<4))
        const int m_ = n_;
        const unsigned aoff0 = m_ * 128 + ((kb * 16) ^ ((m_ & 7) << 4));
        const unsigned aoff1 = m_ * 128 + (((64 + kb * 16)) ^ ((m_ & 7) << 4));
        // prefetch gathers for t=0
        float gxr[4], gxz[4], gxn[4], lbt[4];
#pragma unroll
        for (int q = 0; q < 4; ++q) {
            int id = ids_l[rbase + q][0];
            lbt[q] = labs_l[rbase + q][0];
            const float* p = pre_h + id * G3 + jh;
            gxr[q] = p[0]; gxz[q] = p[64]; gxn[q] = p[128];
        }
        __syncthreads();   // h16s zeros + staging visible

        for (int t = 0; t < Ln; ++t) {
            bf16x8 a0 = *(const bf16x8*)((const char*)h16s + aoff0);
            bf16x8 a1 = *(const bf16x8*)((const char*)h16s + aoff1);
            f32x4 acc[3];
#pragma unroll
            for (int g = 0; g < 3; ++g) {
                f32x4 z4 = {0.f, 0.f, 0.f, 0.f};
                acc[g] = __builtin_amdgcn_mfma_f32_16x16x32_bf16(a0, bfr[g][0], z4, 0, 0, 0);
                acc[g] = __builtin_amdgcn_mfma_f32_16x16x32_bf16(a1, bfr[g][1], acc[g], 0, 0, 0);
            }
            unsigned short hb[4];
#pragma unroll
            for (int q = 0; q < 4; ++q) {
                float xr = fmaf(lbt[q], wlr, gxr[q]);
                float xz = fmaf(lbt[q], wlz, gxz[q]);
                float xn = fmaf(lbt[q], wln, gxn[q]);
                float rg = fsig(xr + acc[0][q] + bhr);
                float zg = fsig(xz + acc[1][q] + bhz);
                float ng = ftanh(fmaf(rg, acc[2][q] + bhn, xn));
                float h  = (1.0f - zg) * ng + zg * hprev[q];
                hprev[q] = h;
                hb[q] = f2bf(h);
                if (t == lenr[q] - 1)
                    M_rv[(seq0 + rbase + q) * Hn + jh] = h;
            }
            // prefetch next step's input gathers (hidden under barrier+MFMA)
            if (t + 1 < Ln) {
#pragma unroll
                for (int q = 0; q < 4; ++q) {
                    int id = ids_l[rbase + q][t + 1];
                    lbt[q] = labs_l[rbase + q][t + 1];
                    const float* p = pre_h + id * G3 + jh;
                    gxr[q] = p[0]; gxz[q] = p[64]; gxn[q] = p[128];
                }
            }
            __syncthreads();   // everyone done reading h16(t)
#pragma unroll
            for (int q = 0; q < 4; ++q) {
                int r = rbase + q;
                unsigned off = r * 128 + (((unsigned)(jh * 2)) ^ ((r & 7) << 4));
                *(unsigned short*)((char*)h16s + off) = hb[q];
            }
            __syncthreads();   // h16(t+1) visible
        }
    } else {
        // =============== INTRA GRU (fp32) ===============
        const int b = blockIdx.x;
        for (int i = tid; i < Sn; i += 256) {
            xid[i] = intra_x[b * Sn + i];
            ysh[i] = (i == 0) ? 0.0f : y[b * Sn + i - 1];
        }
        if (tid < 64) h_i[tid] = 0.0f;
        __syncthreads();

        const int j = tid;
        float whcol[64];
        float bh = 0.0f, wlab = 0.0f, gpre = 0.0f;
        if (j < G3) {
#pragma unroll 8
            for (int k = 0; k < 64; ++k) whcol[k] = Wh_x[k * G3 + j];
            bh   = bh_x[j];
            wlab = Wi_x[64 * G3 + j];
            gpre = pre_x[xid[0] * G3 + j];    // prefetch t=0
        }
        const float4* h4 = (const float4*)h_i;
        for (int t = 0; t < Sn; ++t) {
            if (j < G3) {
                float acch = bh;
#pragma unroll
                for (int k4 = 0; k4 < 16; ++k4) {
                    float4 h4x = h4[k4];
                    acch = fmaf(h4x.x, whcol[4 * k4 + 0], acch);
                    acch = fmaf(h4x.y, whcol[4 * k4 + 1], acch);
                    acch = fmaf(h4x.z, whcol[4 * k4 + 2], acch);
                    acch = fmaf(h4x.w, whcol[4 * k4 + 3], acch);
                }
                gh_b[j] = acch;
                gx_b[j] = fmaf(ysh[t], wlab, gpre);
                if (t + 1 < Sn) gpre = pre_x[xid[t + 1] * G3 + j];  // prefetch
            }
            __syncthreads();
            if (j < 64) {
                float r = fsig(gx_b[j] + gh_b[j]);
                float z = fsig(gx_b[64 + j] + gh_b[64 + j]);
                float n = ftanh(fmaf(r, gh_b[128 + j], gx_b[128 + j]));
                float h = (1.0f - z) * n + z * h_i[j];
                h_i[j] = h;
                h_x[(b * Sn + t) * Hn + j] = h;
            }
            __syncthreads();
        }
    }
}

// ---------------------------------------------------------------------------
// Kernel C: attention over R peers + output MLP; one (b,s) row per block.
// ---------------------------------------------------------------------------
__global__ __launch_bounds__(256) void attn_mlp(
    const float* __restrict__ h_x, const float* __restrict__ M_rv,
    const float* __restrict__ emb, const int* __restrict__ inter_r,
    const float* __restrict__ y,
    const float* __restrict__ Wq,
    const float* __restrict__ Wo, const float* __restrict__ bo,
    const float* __restrict__ W1, const float* __restrict__ b1,
    const float* __restrict__ W2, const float* __restrict__ b2,
    const float* __restrict__ W3, const float* __restrict__ b3,
    float* __restrict__ out)
{
    const int idx = blockIdx.x;
    const int tid = threadIdx.x;
    __shared__ float sh[64], ql[64], Ml[4][64], scl[4], al[4];
    __shared__ float vv[132], ol[64], z1[PH1n], z2[64];
    __shared__ int   rid[4];
    __shared__ float rlab[4];

    if (tid < 64) sh[tid] = h_x[idx * Hn + tid];
    { int r = tid >> 6, j = tid & 63; Ml[r][j] = M_rv[(idx * Rn + r) * Hn + j]; }
    if (tid < 4) {
        rid[tid]  = inter_r[(idx * Rn + tid) * 2];
        rlab[tid] = (float)inter_r[(idx * Rn + tid) * 2 + 1];
    }
    __syncthreads();
    if (tid < 64) {
        float a = 0.0f;
#pragma unroll 8
        for (int k = 0; k < 64; ++k) a = fmaf(sh[k], Wq[k * Hn + tid], a);
        ql[tid] = a;
    }
    __syncthreads();
    if (tid < 4) {
        float a = 0.0f;
#pragma unroll 8
        for (int k = 0; k < 64; ++k) a = fmaf(ql[k], Ml[tid][k], a);
        scl[tid] = a * 0.125f;
    }
    __syncthreads();
    if (tid == 0) {
        float m = fmaxf(fmaxf(scl[0], scl[1]), fmaxf(scl[2], scl[3]));
        float s = 0.0f, e[4];
#pragma unroll
        for (int r = 0; r < 4; ++r) { e[r] = __expf(scl[r] - m); s += e[r]; }
        float inv = 1.0f / s;
#pragma unroll
        for (int r = 0; r < 4; ++r) al[r] = e[r] * inv;
    }
    __syncthreads();
    if (tid < 129) {
        float a = 0.0f;
#pragma unroll
        for (int r = 0; r < 4; ++r) {
            float val;
            if (tid < 64)       val = Ml[r][tid];
            else if (tid < 128) val = emb[rid[r] * En + (tid - 64)];
            else                val = rlab[r];
            a = fmaf(al[r], val, a);
        }
        vv[tid] = a;
    }
    __syncthreads();
    if (tid < 64) {
        float a = bo[tid];
#pragma unroll 8
        for (int k = 0; k < 64; ++k)  a = fmaf(sh[k], Wo[k * Hn + tid], a);
        for (int k = 0; k < 129; ++k) a = fmaf(vv[k], Wo[(64 + k) * Hn + tid], a);
        ol[tid] = tanhf(a);
    }
    __syncthreads();
    {
        float a = b1[tid];
#pragma unroll 8
        for (int k = 0; k < 64; ++k) a = fmaf(ol[k], W1[k * PH1n + tid], a);
        z1[tid] = fmaxf(a, 0.0f);
    }
    __syncthreads();
    if (tid < 64) {
        float a = b2[tid];
#pragma unroll 8
        for (int k = 0; k < PH1n; ++k) a = fmaf(z1[k], W2[k * PH2n + tid], a);
        z2[tid] = fmaxf(a, 0.0f);
    }
    __syncthreads();
    if (tid == 0) {
        float a = b3[0];
#pragma unroll 8
        for (int k = 0; k < 64; ++k) a = fmaf(z2[k], W3[k], a);
        out[idx] = 1.0f / (1.0f + __expf(-a));
        out[NROW + idx] = y[idx];
    }
}

// ---------------------------------------------------------------------------
extern "C" void kernel_launch(void* const* d_in, const int* in_sizes, int n_in,
                              void* d_out, int out_size, void* d_ws, size_t ws_size,
                              hipStream_t stream) {
    const int*   intra_x   = (const int*)d_in[0];
    const int*   inter_his = (const int*)d_in[1];
    const int*   inter_r   = (const int*)d_in[2];
    const float* y         = (const float*)d_in[3];
    const int*   inter_len = (const int*)d_in[5];
    const float* emb  = (const float*)d_in[6];
    const float* Wi_h = (const float*)d_in[7];
    const float* Wh_h = (const float*)d_in[8];
    const float* bi_h = (const float*)d_in[9];
    const float* bh_h = (const float*)d_in[10];
    const float* Wi_x = (const float*)d_in[11];
    const float* Wh_x = (const float*)d_in[12];
    const float* bi_x = (const float*)d_in[13];
    const float* bh_x = (const float*)d_in[14];
    const float* Wq = (const float*)d_in[15];
    const float* Wo = (const float*)d_in[16];
    const float* bo = (const float*)d_in[17];
    const float* W1 = (const float*)d_in[18];
    const float* b1 = (const float*)d_in[19];
    const float* W2 = (const float*)d_in[20];
    const float* b2 = (const float*)d_in[21];
    const float* W3 = (const float*)d_in[22];
    const float* b3 = (const float*)d_in[23];

    float* out = (float*)d_out;
    float* ws  = (float*)d_ws;
    float* pre_h = ws;                       // 1000*192
    float* pre_x = ws + 192000;              // 1000*192
    float* M_rv  = ws + 384000;              // 8192*64
    float* h_x   = ws + 384000 + 524288;     // 16*128*64

    precompute_tab<<<dim3(Vn, 2), 192, 0, stream>>>(emb, Wi_h, bi_h, Wi_x, bi_x,
                                                    pre_h, pre_x);
    gru_fused<<<16 + NSEQ / GP, 256, 0, stream>>>(pre_h, pre_x, inter_his, inter_len,
                                                  Wh_h, bh_h, Wi_h,
                                                  intra_x, y, Wh_x, bh_x, Wi_x,
                                                  M_rv, h_x);
    attn_mlp<<<NROW, 256, 0, stream>>>(h_x, M_rv, emb, inter_r, y,
                                       Wq, Wo, bo, W1, b1, W2, b2, W3, b3, out);
}

// Round 3
// 174.696 us; speedup vs baseline: 1.8550x; 1.4140x over previous
//
#include <hip/hip_runtime.h>
#include <hip/hip_bf16.h>
#include <math.h>

// Problem dims
#define Bn 16
#define Sn 128
#define Rn 4
#define Ln 50
#define En 64
#define Hn 64
#define Vn 1000
#define G3 192          // 3*H
#define PH1n 256
#define PH2n 64
#define NSEQ (Bn*Sn*Rn) // 8192
#define NROW (Bn*Sn)    // 2048
#define GP 16           // sequences per block (MFMA M-tile)

typedef short bf16x8 __attribute__((ext_vector_type(8)));
typedef float f32x4  __attribute__((ext_vector_type(4)));

__device__ __forceinline__ unsigned short f2bf(float x) {
    union { float f; unsigned u; } v; v.f = x;
    unsigned r = v.u + 0x7FFF + ((v.u >> 16) & 1);   // RNE
    return (unsigned short)(r >> 16);
}
__device__ __forceinline__ float fsig(float x)  { return 1.0f / (1.0f + __expf(-x)); }
__device__ __forceinline__ float ftanh(float x) { float e = __expf(2.0f * x); return 1.0f - 2.0f / (e + 1.0f); }

// ---------------------------------------------------------------------------
// Kernel A: precompute input-projection tables
//   pre[v][j] = bi[j] + sum_e emb[v][e] * Wi[e][j]   (rows 0..63 of Wi)
// ---------------------------------------------------------------------------
__global__ __launch_bounds__(192) void precompute_tab(
    const float* __restrict__ emb,
    const float* __restrict__ Wi_h, const float* __restrict__ bi_h,
    const float* __restrict__ Wi_x, const float* __restrict__ bi_x,
    float* __restrict__ pre_h, float* __restrict__ pre_x)
{
    const int v = blockIdx.x;
    const int j = threadIdx.x;
    const float* Wi = blockIdx.y ? Wi_x : Wi_h;
    const float* bi = blockIdx.y ? bi_x : bi_h;
    float* outp = blockIdx.y ? pre_x : pre_h;
    __shared__ float e_l[En];
    if (j < En) e_l[j] = emb[v * En + j];
    __syncthreads();
    float a = bi[j];
#pragma unroll 8
    for (int k = 0; k < En; ++k) a = fmaf(e_l[k], Wi[k * G3 + j], a);
    outp[v * G3 + j] = a;
}

// ---------------------------------------------------------------------------
// Kernel B: unified MFMA GRU.
//   block 0        : intra GRU — M=16 batch sequences, nT=128, h stored every t
//   blocks 1..512  : peer GRU  — M=16 peer sequences,  nT=50, h stored at len-1
// Per step: ds_read A (bf16, XOR-swizzled, double-buffered) -> issue next-step
// gathers -> 6x mfma_16x16x32_bf16 -> gating in-register (fp32 master h) ->
// ds_write h(t+1) -> single barrier.
// ---------------------------------------------------------------------------
__global__ __launch_bounds__(256) void gru_fused(
    const float* __restrict__ pre_h, const float* __restrict__ pre_x,
    const int*   __restrict__ inter_his, const int* __restrict__ inter_len,
    const float* __restrict__ Wh_h, const float* __restrict__ bh_h,
    const float* __restrict__ Wi_h,
    const int*   __restrict__ intra_x, const float* __restrict__ y,
    const float* __restrict__ Wh_x, const float* __restrict__ bh_x,
    const float* __restrict__ Wi_x,
    float* __restrict__ M_rv, float* __restrict__ h_x)
{
    __shared__ __align__(16) unsigned short h16[2][GP * 64];  // 2 x 2KB, swizzled
    __shared__ int   ids_l[GP][Sn];
    __shared__ float labs_l[GP][Sn];

    const int tid = threadIdx.x;
    const bool isIntra = (blockIdx.x == 0);
    const int nT   = isIntra ? Sn : Ln;
    const int seq0 = isIntra ? 0 : ((int)blockIdx.x - 1) * GP;

    const float* pre = isIntra ? pre_x : pre_h;
    const float* Wh  = isIntra ? Wh_x  : Wh_h;
    const float* bh  = isIntra ? bh_x  : bh_h;
    const float* Wi  = isIntra ? Wi_x  : Wi_h;

    if (isIntra) {
        for (int i = tid; i < GP * Sn; i += 256) {
            int r = i >> 7, t = i & (Sn - 1);
            ids_l[r][t]  = intra_x[r * Sn + t];
            labs_l[r][t] = (t == 0) ? 0.0f : y[r * Sn + t - 1];
        }
    } else {
        for (int i = tid; i < GP * Ln; i += 256) {
            int r = i / Ln, t = i % Ln;
            int base = ((seq0 + r) * Ln + t) * 2;
            ids_l[r][t]  = inter_his[base];
            labs_l[r][t] = (float)inter_his[base + 1];
        }
    }
    for (int i = tid; i < GP * 64; i += 256) h16[0][i] = 0;

    const int lane = tid & 63, w = tid >> 6;
    const int n_ = lane & 15, kb = lane >> 4;
    const int jh = w * 16 + n_;          // this wave's hidden-column

    // B fragments: Wh[64][192] -> 3 gate-tiles x 2 K-halves, bf16, in VGPRs
    bf16x8 bfr[3][2];
#pragma unroll
    for (int g = 0; g < 3; ++g)
#pragma unroll
        for (int kh = 0; kh < 2; ++kh) {
            bf16x8 v;
#pragma unroll
            for (int i = 0; i < 8; ++i)
                v[i] = (short)f2bf(Wh[(kh * 32 + kb * 8 + i) * G3 + g * 64 + jh]);
            bfr[g][kh] = v;
        }
    const float bhr = bh[jh], bhz = bh[64 + jh], bhn = bh[128 + jh];
    const float wlr = Wi[64 * G3 + jh];
    const float wlz = Wi[64 * G3 + 64 + jh];
    const float wln = Wi[64 * G3 + 128 + jh];
    const int rbase = kb * 4;            // C rows (sequences) owned by this lane
    int lenr[4];
#pragma unroll
    for (int q = 0; q < 4; ++q)
        lenr[q] = isIntra ? -1 : inter_len[seq0 + rbase + q];
    float hprev[4] = {0.f, 0.f, 0.f, 0.f};

    // addr(row, bytecol) = row*128 + (bytecol ^ ((row&7)<<4))
    const unsigned arow = (unsigned)(n_ * 128);
    const unsigned ac0  = (unsigned)((kb * 16) ^ ((n_ & 7) << 4));
    const unsigned ac1  = (unsigned)((64 + kb * 16) ^ ((n_ & 7) << 4));
    unsigned woff[4];
#pragma unroll
    for (int q = 0; q < 4; ++q) {
        int r = rbase + q;
        woff[q] = (unsigned)(r * 128 + ((jh * 2) ^ ((r & 7) << 4)));
    }

    // double-buffered input-gather registers (static indexing, rule #20)
    float Ar[4], Az[4], An_[4], Al[4];
    float Br[4], Bz[4], Bn_[4], Bl[4];
#pragma unroll
    for (int q = 0; q < 4; ++q) {
        int id = ids_l[rbase + q][0];
        Al[q] = labs_l[rbase + q][0];
        const float* p = pre + id * G3 + jh;
        Ar[q] = p[0]; Az[q] = p[64]; An_[q] = p[128];
    }
    __syncthreads();   // h16[0] zeros + staging visible

    auto step = [&](int t, int cur,
                    float (&gr)[4], float (&gz)[4], float (&gn)[4], float (&gl)[4],
                    float (&pr)[4], float (&pz)[4], float (&pn)[4], float (&pl)[4]) {
        const char* rb = (const char*)&h16[cur][0];
        bf16x8 a0 = *(const bf16x8*)(rb + arow + ac0);
        bf16x8 a1 = *(const bf16x8*)(rb + arow + ac1);
        // issue next step's gathers NOW: MFMA+gating below covers L2 latency,
        // so the vmcnt(0) drain at the barrier finds them already complete.
        if (t + 1 < nT) {
#pragma unroll
            for (int q = 0; q < 4; ++q) {
                int id = ids_l[rbase + q][t + 1];
                pl[q] = labs_l[rbase + q][t + 1];
                const float* p = pre + id * G3 + jh;
                pr[q] = p[0]; pz[q] = p[64]; pn[q] = p[128];
            }
        }
        f32x4 z4 = {0.f, 0.f, 0.f, 0.f};
        f32x4 acc0 = __builtin_amdgcn_mfma_f32_16x16x32_bf16(a0, bfr[0][0], z4, 0, 0, 0);
        f32x4 acc1 = __builtin_amdgcn_mfma_f32_16x16x32_bf16(a0, bfr[1][0], z4, 0, 0, 0);
        f32x4 acc2 = __builtin_amdgcn_mfma_f32_16x16x32_bf16(a0, bfr[2][0], z4, 0, 0, 0);
        acc0 = __builtin_amdgcn_mfma_f32_16x16x32_bf16(a1, bfr[0][1], acc0, 0, 0, 0);
        acc1 = __builtin_amdgcn_mfma_f32_16x16x32_bf16(a1, bfr[1][1], acc1, 0, 0, 0);
        acc2 = __builtin_amdgcn_mfma_f32_16x16x32_bf16(a1, bfr[2][1], acc2, 0, 0, 0);

        char* wb = (char*)&h16[cur ^ 1][0];
#pragma unroll
        for (int q = 0; q < 4; ++q) {
            float xr = fmaf(gl[q], wlr, gr[q]);
            float xz = fmaf(gl[q], wlz, gz[q]);
            float xn = fmaf(gl[q], wln, gn[q]);
            float rg = fsig(xr + acc0[q] + bhr);
            float zg = fsig(xz + acc1[q] + bhz);
            float ng = ftanh(fmaf(rg, acc2[q] + bhn, xn));
            float h  = (1.0f - zg) * ng + zg * hprev[q];
            hprev[q] = h;
            *(unsigned short*)(wb + woff[q]) = f2bf(h);
            if (isIntra) {
                h_x[((rbase + q) * Sn + t) * Hn + jh] = h;
            } else if (t == lenr[q] - 1) {
                M_rv[(seq0 + rbase + q) * Hn + jh] = h;
            }
        }
        __syncthreads();   // h(t+1) visible; one barrier per step
    };

    for (int t = 0; t < nT; t += 2) {       // nT is even (50 / 128)
        step(t,     0, Ar, Az, An_, Al, Br, Bz, Bn_, Bl);
        step(t + 1, 1, Br, Bz, Bn_, Bl, Ar, Az, An_, Al);
    }
}

// ---------------------------------------------------------------------------
// Kernel C: attention over R peers + output MLP; one (b,s) row per block.
// ---------------------------------------------------------------------------
__global__ __launch_bounds__(256) void attn_mlp(
    const float* __restrict__ h_x, const float* __restrict__ M_rv,
    const float* __restrict__ emb, const int* __restrict__ inter_r,
    const float* __restrict__ y,
    const float* __restrict__ Wq,
    const float* __restrict__ Wo, const float* __restrict__ bo,
    const float* __restrict__ W1, const float* __restrict__ b1,
    const float* __restrict__ W2, const float* __restrict__ b2,
    const float* __restrict__ W3, const float* __restrict__ b3,
    float* __restrict__ out)
{
    const int idx = blockIdx.x;
    const int tid = threadIdx.x;
    __shared__ float sh[64], ql[64], Ml[4][64], scl[4], al[4];
    __shared__ float vv[132], ol[64], z1[PH1n], z2[64];
    __shared__ int   rid[4];
    __shared__ float rlab[4];

    if (tid < 64) sh[tid] = h_x[idx * Hn + tid];
    { int r = tid >> 6, j = tid & 63; Ml[r][j] = M_rv[(idx * Rn + r) * Hn + j]; }
    if (tid < 4) {
        rid[tid]  = inter_r[(idx * Rn + tid) * 2];
        rlab[tid] = (float)inter_r[(idx * Rn + tid) * 2 + 1];
    }
    __syncthreads();
    if (tid < 64) {
        float a = 0.0f;
#pragma unroll 8
        for (int k = 0; k < 64; ++k) a = fmaf(sh[k], Wq[k * Hn + tid], a);
        ql[tid] = a;
    }
    __syncthreads();
    if (tid < 4) {
        float a = 0.0f;
#pragma unroll 8
        for (int k = 0; k < 64; ++k) a = fmaf(ql[k], Ml[tid][k], a);
        scl[tid] = a * 0.125f;
    }
    __syncthreads();
    if (tid == 0) {
        float m = fmaxf(fmaxf(scl[0], scl[1]), fmaxf(scl[2], scl[3]));
        float s = 0.0f, e[4];
#pragma unroll
        for (int r = 0; r < 4; ++r) { e[r] = __expf(scl[r] - m); s += e[r]; }
        float inv = 1.0f / s;
#pragma unroll
        for (int r = 0; r < 4; ++r) al[r] = e[r] * inv;
    }
    __syncthreads();
    if (tid < 129) {
        float a = 0.0f;
#pragma unroll
        for (int r = 0; r < 4; ++r) {
            float val;
            if (tid < 64)       val = Ml[r][tid];
            else if (tid < 128) val = emb[rid[r] * En + (tid - 64)];
            else                val = rlab[r];
            a = fmaf(al[r], val, a);
        }
        vv[tid] = a;
    }
    __syncthreads();
    if (tid < 64) {
        float a = bo[tid];
#pragma unroll 8
        for (int k = 0; k < 64; ++k)  a = fmaf(sh[k], Wo[k * Hn + tid], a);
        for (int k = 0; k < 129; ++k) a = fmaf(vv[k], Wo[(64 + k) * Hn + tid], a);
        ol[tid] = tanhf(a);
    }
    __syncthreads();
    {
        float a0 = 0.f, a1 = 0.f;
#pragma unroll
        for (int k = 0; k < 64; k += 2) {
            a0 = fmaf(ol[k],     W1[k * PH1n + tid],       a0);
            a1 = fmaf(ol[k + 1], W1[(k + 1) * PH1n + tid], a1);
        }
        z1[tid] = fmaxf(b1[tid] + (a0 + a1), 0.0f);
    }
    __syncthreads();
    if (tid < 64) {
        float a0 = 0.f, a1 = 0.f, a2 = 0.f, a3 = 0.f;
#pragma unroll
        for (int k = 0; k < PH1n; k += 4) {
            a0 = fmaf(z1[k],     W2[k * PH2n + tid],       a0);
            a1 = fmaf(z1[k + 1], W2[(k + 1) * PH2n + tid], a1);
            a2 = fmaf(z1[k + 2], W2[(k + 2) * PH2n + tid], a2);
            a3 = fmaf(z1[k + 3], W2[(k + 3) * PH2n + tid], a3);
        }
        z2[tid] = fmaxf(b2[tid] + ((a0 + a1) + (a2 + a3)), 0.0f);
    }
    __syncthreads();
    if (tid == 0) {
        float a = b3[0];
#pragma unroll 8
        for (int k = 0; k < 64; ++k) a = fmaf(z2[k], W3[k], a);
        out[idx] = 1.0f / (1.0f + __expf(-a));
        out[NROW + idx] = y[idx];
    }
}

// ---------------------------------------------------------------------------
extern "C" void kernel_launch(void* const* d_in, const int* in_sizes, int n_in,
                              void* d_out, int out_size, void* d_ws, size_t ws_size,
                              hipStream_t stream) {
    const int*   intra_x   = (const int*)d_in[0];
    const int*   inter_his = (const int*)d_in[1];
    const int*   inter_r   = (const int*)d_in[2];
    const float* y         = (const float*)d_in[3];
    const int*   inter_len = (const int*)d_in[5];
    const float* emb  = (const float*)d_in[6];
    const float* Wi_h = (const float*)d_in[7];
    const float* Wh_h = (const float*)d_in[8];
    const float* bi_h = (const float*)d_in[9];
    const float* bh_h = (const float*)d_in[10];
    const float* Wi_x = (const float*)d_in[11];
    const float* Wh_x = (const float*)d_in[12];
    const float* bi_x = (const float*)d_in[13];
    const float* bh_x = (const float*)d_in[14];
    const float* Wq = (const float*)d_in[15];
    const float* Wo = (const float*)d_in[16];
    const float* bo = (const float*)d_in[17];
    const float* W1 = (const float*)d_in[18];
    const float* b1 = (const float*)d_in[19];
    const float* W2 = (const float*)d_in[20];
    const float* b2 = (const float*)d_in[21];
    const float* W3 = (const float*)d_in[22];
    const float* b3 = (const float*)d_in[23];

    float* out = (float*)d_out;
    float* ws  = (float*)d_ws;
    float* pre_h = ws;                       // 1000*192
    float* pre_x = ws + 192000;              // 1000*192
    float* M_rv  = ws + 384000;              // 8192*64
    float* h_x   = ws + 384000 + 524288;     // 16*128*64

    precompute_tab<<<dim3(Vn, 2), 192, 0, stream>>>(emb, Wi_h, bi_h, Wi_x, bi_x,
                                                    pre_h, pre_x);
    gru_fused<<<1 + NSEQ / GP, 256, 0, stream>>>(pre_h, pre_x, inter_his, inter_len,
                                                 Wh_h, bh_h, Wi_h,
                                                 intra_x, y, Wh_x, bh_x, Wi_x,
                                                 M_rv, h_x);
    attn_mlp<<<NROW, 256, 0, stream>>>(h_x, M_rv, emb, inter_r, y,
                                       Wq, Wo, bo, W1, b1, W2, b2, W3, b3, out);
}

// Round 4
// 129.904 us; speedup vs baseline: 2.4946x; 1.3448x over previous
//
#include <hip/hip_runtime.h>
#include <hip/hip_bf16.h>
#include <math.h>

// Problem dims
#define Bn 16
#define Sn 128
#define Rn 4
#define Ln 50
#define En 64
#define Hn 64
#define Vn 1000
#define G3 192          // 3*H
#define PH1n 256
#define PH2n 64
#define NSEQ (Bn*Sn*Rn) // 8192
#define NROW (Bn*Sn)    // 2048
#define GP 16           // peer sequences per block (MFMA M-tile)

typedef short bf16x8 __attribute__((ext_vector_type(8)));
typedef float f32x4  __attribute__((ext_vector_type(4)));
typedef _Float16 half2_t __attribute__((ext_vector_type(2)));
typedef unsigned uint4v __attribute__((ext_vector_type(4)));

__device__ __forceinline__ unsigned short f2bf(float x) {
    union { float f; unsigned u; } v; v.f = x;
    unsigned r = v.u + 0x7FFF + ((v.u >> 16) & 1);   // RNE
    return (unsigned short)(r >> 16);
}
__device__ __forceinline__ float fsig(float x)  { return 1.0f / (1.0f + __expf(-x)); }
__device__ __forceinline__ float ftanh(float x) { float e = __expf(2.0f * x); return 1.0f - 2.0f / (e + 1.0f); }

// Raw barrier: LDS-drain only; global loads/stores float across (no vmcnt(0)).
#define BAR() do { asm volatile("s_waitcnt lgkmcnt(0)" ::: "memory"); \
                   __builtin_amdgcn_s_barrier(); \
                   __builtin_amdgcn_sched_barrier(0); } while (0)

// ---------------------------------------------------------------------------
// Kernel A: precompute input-projection tables
// ---------------------------------------------------------------------------
__global__ __launch_bounds__(192) void precompute_tab(
    const float* __restrict__ emb,
    const float* __restrict__ Wi_h, const float* __restrict__ bi_h,
    const float* __restrict__ Wi_x, const float* __restrict__ bi_x,
    float* __restrict__ pre_h, float* __restrict__ pre_x)
{
    const int v = blockIdx.x;
    const int j = threadIdx.x;
    const float* Wi = blockIdx.y ? Wi_x : Wi_h;
    const float* bi = blockIdx.y ? bi_x : bi_h;
    float* outp = blockIdx.y ? pre_x : pre_h;
    __shared__ float e_l[En];
    if (j < En) e_l[j] = emb[v * En + j];
    __syncthreads();
    float a = bi[j];
#pragma unroll 8
    for (int k = 0; k < En; ++k) a = fmaf(e_l[k], Wi[k * G3 + j], a);
    outp[v * G3 + j] = a;
}

// ---------------------------------------------------------------------------
// Kernel B: fused GRUs.
//   blocks 0..3    : intra GRU — 1 wave per sequence, fdot2, barrier-free
//   blocks 4..515  : peer GRU  — 16 seqs per block, bf16 MFMA, raw barriers
// ---------------------------------------------------------------------------
__global__ __launch_bounds__(256) void gru_fused(
    const float* __restrict__ pre_h, const float* __restrict__ pre_x,
    const int*   __restrict__ inter_his, const int* __restrict__ inter_len,
    const float* __restrict__ Wh_h, const float* __restrict__ bh_h,
    const float* __restrict__ Wi_h,
    const int*   __restrict__ intra_x, const float* __restrict__ y,
    const float* __restrict__ Wh_x, const float* __restrict__ bh_x,
    const float* __restrict__ Wi_x,
    float* __restrict__ M_rv, float* __restrict__ h_x)
{
    __shared__ __align__(16) unsigned short h16[2][GP * 64];  // peer dbuf / intra exch
    __shared__ int   ids_l[GP][Sn];
    __shared__ float labs_l[GP][Sn];

    const int tid = threadIdx.x;
    const int lane = tid & 63, w = tid >> 6;

    if (blockIdx.x >= 4) {
        // =============== PEER GRU (MFMA) ===============
        const int seq0 = ((int)blockIdx.x - 4) * GP;
        for (int i = tid; i < GP * Ln; i += 256) {
            int r = i / Ln, t = i % Ln;
            int base = ((seq0 + r) * Ln + t) * 2;
            ids_l[r][t]  = inter_his[base];
            labs_l[r][t] = (float)inter_his[base + 1];
        }
        for (int i = tid; i < GP * 64; i += 256) h16[0][i] = 0;

        const int n_ = lane & 15, kb = lane >> 4;
        const int jh = w * 16 + n_;
        bf16x8 bfr[3][2];
#pragma unroll
        for (int g = 0; g < 3; ++g)
#pragma unroll
            for (int kh = 0; kh < 2; ++kh) {
                bf16x8 v;
#pragma unroll
                for (int i = 0; i < 8; ++i)
                    v[i] = (short)f2bf(Wh_h[(kh * 32 + kb * 8 + i) * G3 + g * 64 + jh]);
                bfr[g][kh] = v;
            }
        const float bhr = bh_h[jh], bhz = bh_h[64 + jh], bhn = bh_h[128 + jh];
        const float wlr = Wi_h[64 * G3 + jh];
        const float wlz = Wi_h[64 * G3 + 64 + jh];
        const float wln = Wi_h[64 * G3 + 128 + jh];
        const int rbase = kb * 4;
        int lenr[4];
#pragma unroll
        for (int q = 0; q < 4; ++q) lenr[q] = inter_len[seq0 + rbase + q];
        float hprev[4] = {0.f, 0.f, 0.f, 0.f};

        const unsigned arow = (unsigned)(n_ * 128);
        const unsigned ac0  = (unsigned)((kb * 16) ^ ((n_ & 7) << 4));
        const unsigned ac1  = (unsigned)((64 + kb * 16) ^ ((n_ & 7) << 4));
        unsigned woff[4];
#pragma unroll
        for (int q = 0; q < 4; ++q) {
            int r = rbase + q;
            woff[q] = (unsigned)(r * 128 + ((jh * 2) ^ ((r & 7) << 4)));
        }

        float Ar[4], Az[4], An_[4], Al[4];
        float Br[4], Bz[4], Bn_[4], Bl[4];
#pragma unroll
        for (int q = 0; q < 4; ++q) {
            int id = ids_l[rbase + q][0];
            Al[q] = labs_l[rbase + q][0];
            const float* p = pre_h + id * G3 + jh;
            Ar[q] = p[0]; Az[q] = p[64]; An_[q] = p[128];
        }
        __syncthreads();   // setup barrier (full drain OK, once)

        auto step = [&](int t, int cur,
                        float (&gr)[4], float (&gz)[4], float (&gn)[4], float (&gl)[4],
                        float (&pr)[4], float (&pz)[4], float (&pn)[4], float (&pl)[4]) {
            const char* rb = (const char*)&h16[cur][0];
            bf16x8 a0 = *(const bf16x8*)(rb + arow + ac0);
            bf16x8 a1 = *(const bf16x8*)(rb + arow + ac1);
            if (t + 1 < Ln) {
#pragma unroll
                for (int q = 0; q < 4; ++q) {
                    int id = ids_l[rbase + q][t + 1];
                    pl[q] = labs_l[rbase + q][t + 1];
                    const float* p = pre_h + id * G3 + jh;
                    pr[q] = p[0]; pz[q] = p[64]; pn[q] = p[128];
                }
            }
            f32x4 z4 = {0.f, 0.f, 0.f, 0.f};
            f32x4 acc0 = __builtin_amdgcn_mfma_f32_16x16x32_bf16(a0, bfr[0][0], z4, 0, 0, 0);
            f32x4 acc1 = __builtin_amdgcn_mfma_f32_16x16x32_bf16(a0, bfr[1][0], z4, 0, 0, 0);
            f32x4 acc2 = __builtin_amdgcn_mfma_f32_16x16x32_bf16(a0, bfr[2][0], z4, 0, 0, 0);
            acc0 = __builtin_amdgcn_mfma_f32_16x16x32_bf16(a1, bfr[0][1], acc0, 0, 0, 0);
            acc1 = __builtin_amdgcn_mfma_f32_16x16x32_bf16(a1, bfr[1][1], acc1, 0, 0, 0);
            acc2 = __builtin_amdgcn_mfma_f32_16x16x32_bf16(a1, bfr[2][1], acc2, 0, 0, 0);

            char* wb = (char*)&h16[cur ^ 1][0];
#pragma unroll
            for (int q = 0; q < 4; ++q) {
                float xr = fmaf(gl[q], wlr, gr[q]);
                float xz = fmaf(gl[q], wlz, gz[q]);
                float xn = fmaf(gl[q], wln, gn[q]);
                float rg = fsig(xr + acc0[q] + bhr);
                float zg = fsig(xz + acc1[q] + bhz);
                float ng = ftanh(fmaf(rg, acc2[q] + bhn, xn));
                float h  = (1.0f - zg) * ng + zg * hprev[q];
                hprev[q] = h;
                *(unsigned short*)(wb + woff[q]) = f2bf(h);
                if (t == lenr[q] - 1)
                    M_rv[(seq0 + rbase + q) * Hn + jh] = h;
            }
            BAR();   // LDS-drain only; gathers + stores stay in flight
        };

        for (int t = 0; t < Ln; t += 2) {
            step(t,     0, Ar, Az, An_, Al, Br, Bz, Bn_, Bl);
            step(t + 1, 1, Br, Bz, Bn_, Bl, Ar, Az, An_, Al);
        }
    } else {
        // =============== INTRA GRU: 1 wave = 1 sequence, barrier-free ======
        const int sg = blockIdx.x * 4 + w;           // global sequence 0..15
        for (int i = tid; i < 4 * Sn; i += 256) {
            int r = i >> 7, t = i & (Sn - 1);
            ids_l[r][t]  = intra_x[(blockIdx.x * 4 + r) * Sn + t];
            labs_l[r][t] = (t == 0) ? 0.0f : y[(blockIdx.x * 4 + r) * Sn + t - 1];
        }
        __syncthreads();   // staging visible (once)

        const int j = lane;
        // Wh_x columns {j, 64+j, 128+j} packed f16 pairs along k
        half2_t wf[3][32];
#pragma unroll
        for (int g = 0; g < 3; ++g)
#pragma unroll
            for (int p = 0; p < 32; ++p) {
                half2_t v;
                v[0] = (_Float16)Wh_x[(2 * p)     * G3 + g * 64 + j];
                v[1] = (_Float16)Wh_x[(2 * p + 1) * G3 + g * 64 + j];
                wf[g][p] = v;
            }
        const float bhr = bh_x[j], bhz = bh_x[64 + j], bhn = bh_x[128 + j];
        const float wlr = Wi_x[64 * G3 + j];
        const float wlz = Wi_x[64 * G3 + 64 + j];
        const float wln = Wi_x[64 * G3 + 128 + j];

        // per-wave exchange buffer: 64 f16 (128 B), overlaid on h16
        _Float16* hx = (_Float16*)&h16[0][0] + w * 64;
        hx[j] = (_Float16)0.0f;     // zero-init h
        // f32 master h for this lane's hidden unit
        float hmy = 0.0f;
        // prefetch t=0
        int id0 = ids_l[w][0];
        float lb = labs_l[w][0];
        float gxr = pre_x[id0 * G3 + j];
        float gxz = pre_x[id0 * G3 + 64 + j];
        float gxn = pre_x[id0 * G3 + 128 + j];
        asm volatile("s_waitcnt lgkmcnt(0)" ::: "memory");  // hx zeros visible (same wave)

        for (int t = 0; t < Sn; ++t) {
            // read h (broadcast, 8x b128) and accumulate 96 fdot2
            uint4v qv[8];
#pragma unroll
            for (int i2 = 0; i2 < 8; ++i2) qv[i2] = ((const uint4v*)hx)[i2];
            float dr[4] = {0.f, 0.f, 0.f, 0.f};
            float dz[4] = {0.f, 0.f, 0.f, 0.f};
            float dn[4] = {0.f, 0.f, 0.f, 0.f};
#pragma unroll
            for (int i2 = 0; i2 < 8; ++i2) {
#pragma unroll
                for (int k = 0; k < 4; ++k) {
                    const int p = i2 * 4 + k;
                    half2_t hv = __builtin_bit_cast(half2_t, qv[i2][k]);
                    dr[p & 3] = __builtin_amdgcn_fdot2(hv, wf[0][p], dr[p & 3], false);
                    dz[p & 3] = __builtin_amdgcn_fdot2(hv, wf[1][p], dz[p & 3], false);
                    dn[p & 3] = __builtin_amdgcn_fdot2(hv, wf[2][p], dn[p & 3], false);
                }
            }
            float ghr = (dr[0] + dr[1]) + (dr[2] + dr[3]) + bhr;
            float ghz = (dz[0] + dz[1]) + (dz[2] + dz[3]) + bhz;
            float ghn = (dn[0] + dn[1]) + (dn[2] + dn[3]) + bhn;
            float xr = fmaf(lb, wlr, gxr);
            float xz = fmaf(lb, wlz, gxz);
            float xn = fmaf(lb, wln, gxn);
            // prefetch next step (floats under counted vmcnt)
            if (t + 1 < Sn) {
                int id = ids_l[w][t + 1];
                lb = labs_l[w][t + 1];
                gxr = pre_x[id * G3 + j];
                gxz = pre_x[id * G3 + 64 + j];
                gxn = pre_x[id * G3 + 128 + j];
            }
            float rg = fsig(xr + ghr);
            float zg = fsig(xz + ghz);
            float ng = ftanh(fmaf(rg, ghn, xn));
            float h  = (1.0f - zg) * ng + zg * hmy;
            hmy = h;
            h_x[(sg * Sn + t) * Hn + j] = h;     // store floats freely
            hx[j] = (_Float16)h;                 // same-wave ds_write; lgkmcnt
                                                 // auto-inserted before next read
        }
    }
}

// ---------------------------------------------------------------------------
// Kernel C: attention over R peers + output MLP; one (b,s) row per block.
// ---------------------------------------------------------------------------
__global__ __launch_bounds__(256) void attn_mlp(
    const float* __restrict__ h_x, const float* __restrict__ M_rv,
    const float* __restrict__ emb, const int* __restrict__ inter_r,
    const float* __restrict__ y,
    const float* __restrict__ Wq,
    const float* __restrict__ Wo, const float* __restrict__ bo,
    const float* __restrict__ W1, const float* __restrict__ b1,
    const float* __restrict__ W2, const float* __restrict__ b2,
    const float* __restrict__ W3, const float* __restrict__ b3,
    float* __restrict__ out)
{
    const int idx = blockIdx.x;
    const int tid = threadIdx.x;
    __shared__ float sh[64], ql[64], Ml[4][64], scl[4], al[4];
    __shared__ float vv[132], ol[64], z1[PH1n], z2[64];
    __shared__ int   rid[4];
    __shared__ float rlab[4];

    if (tid < 64) sh[tid] = h_x[idx * Hn + tid];
    { int r = tid >> 6, j = tid & 63; Ml[r][j] = M_rv[(idx * Rn + r) * Hn + j]; }
    if (tid < 4) {
        rid[tid]  = inter_r[(idx * Rn + tid) * 2];
        rlab[tid] = (float)inter_r[(idx * Rn + tid) * 2 + 1];
    }
    __syncthreads();
    if (tid < 64) {
        float a = 0.0f;
#pragma unroll 8
        for (int k = 0; k < 64; ++k) a = fmaf(sh[k], Wq[k * Hn + tid], a);
        ql[tid] = a;
    }
    __syncthreads();
    if (tid < 4) {
        float a = 0.0f;
#pragma unroll 8
        for (int k = 0; k < 64; ++k) a = fmaf(ql[k], Ml[tid][k], a);
        scl[tid] = a * 0.125f;
    }
    __syncthreads();
    if (tid == 0) {
        float m = fmaxf(fmaxf(scl[0], scl[1]), fmaxf(scl[2], scl[3]));
        float s = 0.0f, e[4];
#pragma unroll
        for (int r = 0; r < 4; ++r) { e[r] = __expf(scl[r] - m); s += e[r]; }
        float inv = 1.0f / s;
#pragma unroll
        for (int r = 0; r < 4; ++r) al[r] = e[r] * inv;
    }
    __syncthreads();
    if (tid < 129) {
        float a = 0.0f;
#pragma unroll
        for (int r = 0; r < 4; ++r) {
            float val;
            if (tid < 64)       val = Ml[r][tid];
            else if (tid < 128) val = emb[rid[r] * En + (tid - 64)];
            else                val = rlab[r];
            a = fmaf(al[r], val, a);
        }
        vv[tid] = a;
    }
    __syncthreads();
    if (tid < 64) {
        float a = bo[tid];
#pragma unroll 8
        for (int k = 0; k < 64; ++k)  a = fmaf(sh[k], Wo[k * Hn + tid], a);
        for (int k = 0; k < 129; ++k) a = fmaf(vv[k], Wo[(64 + k) * Hn + tid], a);
        ol[tid] = tanhf(a);
    }
    __syncthreads();
    {
        float a0 = 0.f, a1 = 0.f;
#pragma unroll
        for (int k = 0; k < 64; k += 2) {
            a0 = fmaf(ol[k],     W1[k * PH1n + tid],       a0);
            a1 = fmaf(ol[k + 1], W1[(k + 1) * PH1n + tid], a1);
        }
        z1[tid] = fmaxf(b1[tid] + (a0 + a1), 0.0f);
    }
    __syncthreads();
    if (tid < 64) {
        float a0 = 0.f, a1 = 0.f, a2 = 0.f, a3 = 0.f;
#pragma unroll
        for (int k = 0; k < PH1n; k += 4) {
            a0 = fmaf(z1[k],     W2[k * PH2n + tid],       a0);
            a1 = fmaf(z1[k + 1], W2[(k + 1) * PH2n + tid], a1);
            a2 = fmaf(z1[k + 2], W2[(k + 2) * PH2n + tid], a2);
            a3 = fmaf(z1[k + 3], W2[(k + 3) * PH2n + tid], a3);
        }
        z2[tid] = fmaxf(b2[tid] + ((a0 + a1) + (a2 + a3)), 0.0f);
    }
    __syncthreads();
    if (tid == 0) {
        float a = b3[0];
#pragma unroll 8
        for (int k = 0; k < 64; ++k) a = fmaf(z2[k], W3[k], a);
        out[idx] = 1.0f / (1.0f + __expf(-a));
        out[NROW + idx] = y[idx];
    }
}

// ---------------------------------------------------------------------------
extern "C" void kernel_launch(void* const* d_in, const int* in_sizes, int n_in,
                              void* d_out, int out_size, void* d_ws, size_t ws_size,
                              hipStream_t stream) {
    const int*   intra_x   = (const int*)d_in[0];
    const int*   inter_his = (const int*)d_in[1];
    const int*   inter_r   = (const int*)d_in[2];
    const float* y         = (const float*)d_in[3];
    const int*   inter_len = (const int*)d_in[5];
    const float* emb  = (const float*)d_in[6];
    const float* Wi_h = (const float*)d_in[7];
    const float* Wh_h = (const float*)d_in[8];
    const float* bi_h = (const float*)d_in[9];
    const float* bh_h = (const float*)d_in[10];
    const float* Wi_x = (const float*)d_in[11];
    const float* Wh_x = (const float*)d_in[12];
    const float* bi_x = (const float*)d_in[13];
    const float* bh_x = (const float*)d_in[14];
    const float* Wq = (const float*)d_in[15];
    const float* Wo = (const float*)d_in[16];
    const float* bo = (const float*)d_in[17];
    const float* W1 = (const float*)d_in[18];
    const float* b1 = (const float*)d_in[19];
    const float* W2 = (const float*)d_in[20];
    const float* b2 = (const float*)d_in[21];
    const float* W3 = (const float*)d_in[22];
    const float* b3 = (const float*)d_in[23];

    float* out = (float*)d_out;
    float* ws  = (float*)d_ws;
    float* pre_h = ws;                       // 1000*192
    float* pre_x = ws + 192000;              // 1000*192
    float* M_rv  = ws + 384000;              // 8192*64
    float* h_x   = ws + 384000 + 524288;     // 16*128*64

    precompute_tab<<<dim3(Vn, 2), 192, 0, stream>>>(emb, Wi_h, bi_h, Wi_x, bi_x,
                                                    pre_h, pre_x);
    gru_fused<<<4 + NSEQ / GP, 256, 0, stream>>>(pre_h, pre_x, inter_his, inter_len,
                                                 Wh_h, bh_h, Wi_h,
                                                 intra_x, y, Wh_x, bh_x, Wi_x,
                                                 M_rv, h_x);
    attn_mlp<<<NROW, 256, 0, stream>>>(h_x, M_rv, emb, inter_r, y,
                                       Wq, Wo, bo, W1, b1, W2, b2, W3, b3, out);
}